// Round 3
// baseline (711.940 us; speedup 1.0000x reference)
//
#include <hip/hip_runtime.h>
#include <hip/hip_bf16.h>
#include <math.h>

#define LSEQ 16384   // H*W per batch
#define DIN  192
#define NST  16
#define GCH  256     // scan chunks
#define TCH  64      // chunk length (GCH*TCH == LSEQ)

__device__ __forceinline__ float siluf(float x) { return x / (1.0f + __expf(-x)); }

// ---------------- 1. bilinear upsample 2x (align_corners) ----------------
__global__ __launch_bounds__(256) void k_upsample(const float* __restrict__ x, float* __restrict__ up) {
  int idx = blockIdx.x * 256 + threadIdx.x;
  if (idx >= 2 * 96 * LSEQ) return;
  int ow = idx & 127, oh = (idx >> 7) & 127, bc = idx >> 14;
  float pr = oh * (63.0f / 127.0f); int r0 = (int)pr; float rw = pr - (float)r0; int r1 = min(r0 + 1, 63);
  float pc = ow * (63.0f / 127.0f); int c0 = (int)pc; float cw = pc - (float)c0; int c1 = min(c0 + 1, 63);
  const float* xp = x + (size_t)bc * 4096;
  float v00 = xp[r0 * 64 + c0], v01 = xp[r0 * 64 + c1];
  float v10 = xp[r1 * 64 + c0], v11 = xp[r1 * 64 + c1];
  float top = v00 + (v10 - v00) * rw;
  float bot = v01 + (v11 - v01) * rw;
  up[idx] = top + (bot - top) * cw;
}

// ---------------- 2. generic 1x1 conv (planar in/out), Cin % 48 == 0 ----------------
// grid (256 pixel-tiles of 64, B), block 256. out 96 channels.
__global__ __launch_bounds__(256) void k_conv1x1(
    const float* __restrict__ inA, int CA, const float* __restrict__ inB, int CB,
    const float* __restrict__ Wg, const float* __restrict__ bias,
    float* __restrict__ out, int Cin) {
  __shared__ float in_t[48 * 64];
  __shared__ float w_t[96 * 49];
  int b = blockIdx.y, p0 = blockIdx.x * 64;
  int tid = threadIdx.x, tx = tid & 15, ty = tid >> 4;
  float acc[6][4];
#pragma unroll
  for (int j = 0; j < 6; j++) { acc[j][0] = acc[j][1] = acc[j][2] = acc[j][3] = 0.f; }
  int nch = Cin / 48;
  for (int cc = 0; cc < nch; cc++) {
    for (int i = tid; i < 48 * 64; i += 256) {
      int ic = i >> 6, px = i & 63;
      int c = cc * 48 + ic;
      const float* src = (c < CA) ? (inA + ((size_t)b * CA + c) * LSEQ)
                                  : (inB + ((size_t)b * CB + (c - CA)) * LSEQ);
      in_t[i] = src[p0 + px];
    }
    for (int i = tid; i < 96 * 48; i += 256) {
      int oc = i / 48, ic = i - oc * 48;
      w_t[oc * 49 + ic] = Wg[(size_t)oc * Cin + cc * 48 + ic];
    }
    __syncthreads();
#pragma unroll 4
    for (int ic = 0; ic < 48; ic++) {
      float4 iv = *(const float4*)&in_t[ic * 64 + tx * 4];
#pragma unroll
      for (int j = 0; j < 6; j++) {
        float wv = w_t[(ty * 6 + j) * 49 + ic];
        acc[j][0] = fmaf(wv, iv.x, acc[j][0]);
        acc[j][1] = fmaf(wv, iv.y, acc[j][1]);
        acc[j][2] = fmaf(wv, iv.z, acc[j][2]);
        acc[j][3] = fmaf(wv, iv.w, acc[j][3]);
      }
    }
    __syncthreads();
  }
#pragma unroll
  for (int j = 0; j < 6; j++) {
    int oc = ty * 6 + j;
    float bv = bias[oc];
    float4 o = make_float4(acc[j][0] + bv, acc[j][1] + bv, acc[j][2] + bv, acc[j][3] + bv);
    *(float4*)&out[((size_t)b * 96 + oc) * LSEQ + p0 + tx * 4] = o;
  }
}

// ---------------- 3. 3x3 conv, 96->96, pad 1 ----------------
// grid (64 spatial tiles 16x16, 6 oc-groups of 16, B), block 256
__global__ __launch_bounds__(256) void k_conv3x3(const float* __restrict__ in,
    const float* __restrict__ Wg, const float* __restrict__ bias, float* __restrict__ out) {
  __shared__ float in_t[16 * 342];   // [16 ic][18 rows][19 stride]
  __shared__ float w_t[16 * 144];    // [16 oc][16 ic][9]
  int b = blockIdx.z, ocg = blockIdx.y, tile = blockIdx.x;
  int ty0 = (tile >> 3) * 16, tx0 = (tile & 7) * 16;
  int tid = threadIdx.x, tx = tid & 3, ty = (tid >> 2) & 15, tz = tid >> 6;
  float acc[4][4];
#pragma unroll
  for (int j = 0; j < 4; j++) { acc[j][0] = acc[j][1] = acc[j][2] = acc[j][3] = 0.f; }
  for (int cc = 0; cc < 6; cc++) {
    for (int i = tid; i < 16 * 324; i += 256) {
      int ic = i / 324, rem = i - ic * 324;
      int r = rem / 18, cx = rem - r * 18;
      int gy = ty0 - 1 + r, gx = tx0 - 1 + cx;
      float v = 0.f;
      if (gy >= 0 && gy < 128 && gx >= 0 && gx < 128)
        v = in[(((size_t)b * 96 + cc * 16 + ic) * 128 + gy) * 128 + gx];
      in_t[ic * 342 + r * 19 + cx] = v;
    }
    for (int i = tid; i < 16 * 144; i += 256) {
      int oc = i / 144, rest = i - oc * 144;
      w_t[i] = Wg[((size_t)(ocg * 16 + oc) * 96 + cc * 16) * 9 + rest];
    }
    __syncthreads();
    for (int ic = 0; ic < 16; ic++) {
      float v[3][6];
      const float* bp = &in_t[ic * 342];
#pragma unroll
      for (int ky = 0; ky < 3; ky++)
#pragma unroll
        for (int cxx = 0; cxx < 6; cxx++)
          v[ky][cxx] = bp[(ty + ky) * 19 + tx * 4 + cxx];
#pragma unroll
      for (int jo = 0; jo < 4; jo++) {
        const float* wp = &w_t[(tz * 4 + jo) * 144 + ic * 9];
#pragma unroll
        for (int ky = 0; ky < 3; ky++)
#pragma unroll
          for (int kx = 0; kx < 3; kx++) {
            float wv = wp[ky * 3 + kx];
#pragma unroll
            for (int px = 0; px < 4; px++)
              acc[jo][px] = fmaf(wv, v[ky][kx + px], acc[jo][px]);
          }
      }
    }
    __syncthreads();
  }
#pragma unroll
  for (int jo = 0; jo < 4; jo++) {
    int oc = ocg * 16 + tz * 4 + jo;
    float bv = bias[oc];
    float4 o = make_float4(acc[jo][0] + bv, acc[jo][1] + bv, acc[jo][2] + bv, acc[jo][3] + bv);
    *(float4*)&out[(((size_t)b * 96 + oc) * 128 + ty0 + ty) * 128 + tx0 + tx * 4] = o;
  }
}

// ---------------- 4. instance-norm stats ----------------
__global__ __launch_bounds__(256) void k_stats(const float* __restrict__ h, float* __restrict__ stats) {
  int bc = blockIdx.x;
  const float* p = h + (size_t)bc * LSEQ;
  float s = 0.f, ss = 0.f;
  for (int i = threadIdx.x; i < LSEQ; i += 256) { float v = p[i]; s += v; ss = fmaf(v, v, ss); }
  __shared__ float rs[256], rss[256];
  int tid = threadIdx.x;
  rs[tid] = s; rss[tid] = ss; __syncthreads();
  for (int o = 128; o > 0; o >>= 1) {
    if (tid < o) { rs[tid] += rs[tid + o]; rss[tid] += rss[tid + o]; }
    __syncthreads();
  }
  if (tid == 0) {
    float m = rs[0] * (1.0f / LSEQ);
    float var = rss[0] * (1.0f / LSEQ) - m * m;
    stats[bc * 2] = m;
    stats[bc * 2 + 1] = rsqrtf(fmaxf(var, 0.f) + 1e-5f);
  }
}

// ---------------- 5. normalize + SELU ----------------
__global__ __launch_bounds__(256) void k_normselu(const float* __restrict__ h,
    const float* __restrict__ stats, float* __restrict__ Lx) {
  int idx = blockIdx.x * 256 + threadIdx.x;
  if (idx >= 2 * 96 * LSEQ) return;
  int bc = idx >> 14;
  float v = (h[idx] - stats[bc * 2]) * stats[bc * 2 + 1];
  const float kS = 1.0507009873554805f, kA = 1.6732632423543772f;
  Lx[idx] = v > 0.f ? kS * v : kS * kA * expm1f(v);
}

// ---------------- 6. in_proj: xz[b,l,384] = Lx[b,:,l] @ Win^T ----------------
// grid (256 l-tiles of 64, 3 j-groups of 128, B), block 256
__global__ __launch_bounds__(256) void k_inproj(const float* __restrict__ Lx,
    const float* __restrict__ Win, float* __restrict__ xz) {
  __shared__ float in_t[48 * 64];
  __shared__ float w_t[128 * 49];
  int b = blockIdx.z, jg = blockIdx.y, l0 = blockIdx.x * 64;
  int tid = threadIdx.x, tx = tid & 15, ty = tid >> 4;
  float acc[8][4];
#pragma unroll
  for (int j = 0; j < 8; j++) { acc[j][0] = acc[j][1] = acc[j][2] = acc[j][3] = 0.f; }
  for (int cc = 0; cc < 2; cc++) {
    for (int i = tid; i < 48 * 64; i += 256) {
      int c = i >> 6, px = i & 63;
      in_t[i] = Lx[((size_t)b * 96 + cc * 48 + c) * LSEQ + l0 + px];
    }
    for (int i = tid; i < 128 * 48; i += 256) {
      int j = i / 48, c = i - j * 48;
      w_t[j * 49 + c] = Win[(size_t)(jg * 128 + j) * 96 + cc * 48 + c];
    }
    __syncthreads();
#pragma unroll 4
    for (int c = 0; c < 48; c++) {
      float4 lv = *(const float4*)&in_t[c * 64 + ty * 4];
#pragma unroll
      for (int jq = 0; jq < 8; jq++) {
        float wv = w_t[(jq * 16 + tx) * 49 + c];
        acc[jq][0] = fmaf(wv, lv.x, acc[jq][0]);
        acc[jq][1] = fmaf(wv, lv.y, acc[jq][1]);
        acc[jq][2] = fmaf(wv, lv.z, acc[jq][2]);
        acc[jq][3] = fmaf(wv, lv.w, acc[jq][3]);
      }
    }
    __syncthreads();
  }
#pragma unroll
  for (int jq = 0; jq < 8; jq++) {
    int j = jg * 128 + jq * 16 + tx;
#pragma unroll
    for (int px = 0; px < 4; px++) {
      int l = l0 + ty * 4 + px;
      xz[((size_t)b * LSEQ + l) * 384 + j] = acc[jq][px];
    }
  }
}

// ---------------- 7. causal depthwise conv1d + SiLU ----------------
__global__ __launch_bounds__(256) void k_conv1d(const float* __restrict__ xz,
    const float* __restrict__ w1d, const float* __restrict__ b1d, float* __restrict__ u) {
  int gid = blockIdx.x * 256 + threadIdx.x;
  if (gid >= 2 * LSEQ * DIN) return;
  int d = gid % DIN, bl = gid / DIN;
  int l = bl & (LSEQ - 1);
  float4 w = *(const float4*)&w1d[d * 4];
  float wv[4] = {w.x, w.y, w.z, w.w};
  float acc = b1d[d];
#pragma unroll
  for (int k = 0; k < 4; k++) {
    int lk = l - 3 + k;
    if (lk >= 0) acc = fmaf(wv[k], xz[(size_t)(bl - 3 + k) * 384 + d], acc);
  }
  u[gid] = siluf(acc);
}

// ---------------- 8. x_proj: xdbl[bl,38] = u[bl,:] @ Wx^T ----------------
__global__ __launch_bounds__(256) void k_xproj(const float* __restrict__ u,
    const float* __restrict__ Wx, float* __restrict__ xdbl) {
  int gid = blockIdx.x * 256 + threadIdx.x;
  if (gid >= 2 * LSEQ * 38) return;
  int bl = gid / 38, j = gid - bl * 38;
  const float* up = u + (size_t)bl * DIN;
  const float* wp = Wx + (size_t)j * DIN;
  float acc = 0.f;
#pragma unroll 4
  for (int k = 0; k < DIN; k += 4) {
    float4 a = *(const float4*)&up[k];
    float4 w = *(const float4*)&wp[k];
    acc = fmaf(a.x, w.x, acc); acc = fmaf(a.y, w.y, acc);
    acc = fmaf(a.z, w.z, acc); acc = fmaf(a.w, w.w, acc);
  }
  xdbl[gid] = acc;
}

// ---------------- 9. dt_proj + softplus ----------------
__global__ __launch_bounds__(256) void k_dtproj(const float* __restrict__ xdbl,
    const float* __restrict__ Wdt, const float* __restrict__ bdt, float* __restrict__ dt) {
  int gid = blockIdx.x * 256 + threadIdx.x;
  if (gid >= 2 * LSEQ * DIN) return;
  int d = gid % DIN, bl = gid / DIN;
  const float* xp = xdbl + (size_t)bl * 38;
  const float* wp = Wdt + d * 6;
  float acc = bdt[d];
#pragma unroll
  for (int r = 0; r < 6; r++) acc = fmaf(xp[r], wp[r], acc);
  dt[gid] = acc > 20.f ? acc : log1pf(__expf(acc));
}

// ---------------- 10. scan phase A: per-chunk (prod a, h_end | h0=0) ----------------
// grid (GCH, B), block 192 (thread = d)
__global__ __launch_bounds__(192) void k_scanA(const float* __restrict__ dt,
    const float* __restrict__ u, const float* __restrict__ xdbl,
    const float* __restrict__ Alog, float* __restrict__ chA, float* __restrict__ chB) {
  int b = blockIdx.y, g = blockIdx.x, d = threadIdx.x;
  __shared__ float Bs[TCH * 16];
  for (int i = threadIdx.x; i < TCH * 16; i += 192) {
    int t = i >> 4, n = i & 15;
    Bs[i] = xdbl[(size_t)(b * LSEQ + g * TCH + t) * 38 + 6 + n];
  }
  float ac[16];
#pragma unroll
  for (int n = 0; n < 16; n++) ac[n] = -__expf(Alog[d * 16 + n]);
  __syncthreads();
  float ap[16], hb[16];
#pragma unroll
  for (int n = 0; n < 16; n++) { ap[n] = 1.f; hb[n] = 0.f; }
  for (int t = 0; t < TCH; t++) {
    size_t base = (size_t)(b * LSEQ + g * TCH + t);
    float dtv = dt[base * DIN + d];
    float uv = u[base * DIN + d];
    float du = dtv * uv;
    float bs[16];
    const float4* src = (const float4*)&Bs[t * 16];
#pragma unroll
    for (int q = 0; q < 4; q++) {
      float4 v = src[q];
      bs[q * 4] = v.x; bs[q * 4 + 1] = v.y; bs[q * 4 + 2] = v.z; bs[q * 4 + 3] = v.w;
    }
#pragma unroll
    for (int n = 0; n < 16; n++) {
      float e = __expf(dtv * ac[n]);
      ap[n] *= e;
      hb[n] = fmaf(hb[n], e, du * bs[n]);
    }
  }
  size_t co = ((size_t)(b * GCH + g) * DIN + d) * 16;
#pragma unroll
  for (int q = 0; q < 4; q++) {
    ((float4*)(chA + co))[q] = make_float4(ap[q * 4], ap[q * 4 + 1], ap[q * 4 + 2], ap[q * 4 + 3]);
    ((float4*)(chB + co))[q] = make_float4(hb[q * 4], hb[q * 4 + 1], hb[q * 4 + 2], hb[q * 4 + 3]);
  }
}

// ---------------- 11. scan phase B: exclusive scan across chunks ----------------
__global__ __launch_bounds__(256) void k_scanB(const float* __restrict__ chA,
    const float* __restrict__ chB, float* __restrict__ h0) {
  int tid = blockIdx.x * 256 + threadIdx.x;
  if (tid >= 2 * DIN * 16) return;
  int b = tid / (DIN * 16), rem = tid - b * DIN * 16;
  float h = 0.f;
#pragma unroll 4
  for (int g = 0; g < GCH; g++) {
    size_t off = (size_t)(b * GCH + g) * (DIN * 16) + rem;
    h0[off] = h;
    h = fmaf(h, chA[off], chB[off]);
  }
}

// ---------------- 12. scan phase C: replay with init state; fuse +u*D, *silu(z) ----------------
// grid (GCH, B), block 192
__global__ __launch_bounds__(192) void k_scanC(const float* __restrict__ dt,
    const float* __restrict__ u, const float* __restrict__ xdbl,
    const float* __restrict__ xz, const float* __restrict__ Alog,
    const float* __restrict__ Dp, const float* __restrict__ h0, float* __restrict__ y) {
  int b = blockIdx.y, g = blockIdx.x, d = threadIdx.x;
  __shared__ float Bs[TCH * 16], Cs[TCH * 16];
  for (int i = threadIdx.x; i < TCH * 16; i += 192) {
    int t = i >> 4, n = i & 15;
    size_t rb = (size_t)(b * LSEQ + g * TCH + t) * 38;
    Bs[i] = xdbl[rb + 6 + n];
    Cs[i] = xdbl[rb + 22 + n];
  }
  float ac[16];
#pragma unroll
  for (int n = 0; n < 16; n++) ac[n] = -__expf(Alog[d * 16 + n]);
  float Dd = Dp[d];
  __syncthreads();
  size_t co = ((size_t)(b * GCH + g) * DIN + d) * 16;
  float h[16];
#pragma unroll
  for (int q = 0; q < 4; q++) {
    float4 v = ((const float4*)(h0 + co))[q];
    h[q * 4] = v.x; h[q * 4 + 1] = v.y; h[q * 4 + 2] = v.z; h[q * 4 + 3] = v.w;
  }
  for (int t = 0; t < TCH; t++) {
    size_t base = (size_t)(b * LSEQ + g * TCH + t);
    float dtv = dt[base * DIN + d];
    float uv = u[base * DIN + d];
    float zv = xz[base * 384 + DIN + d];
    float du = dtv * uv;
    float bs[16], cs[16];
    const float4* sb = (const float4*)&Bs[t * 16];
    const float4* sc = (const float4*)&Cs[t * 16];
#pragma unroll
    for (int q = 0; q < 4; q++) {
      float4 vb = sb[q], vc = sc[q];
      bs[q * 4] = vb.x; bs[q * 4 + 1] = vb.y; bs[q * 4 + 2] = vb.z; bs[q * 4 + 3] = vb.w;
      cs[q * 4] = vc.x; cs[q * 4 + 1] = vc.y; cs[q * 4 + 2] = vc.z; cs[q * 4 + 3] = vc.w;
    }
    float y0 = 0.f, y1 = 0.f, y2 = 0.f, y3 = 0.f;
#pragma unroll
    for (int n = 0; n < 16; n++) {
      float e = __expf(dtv * ac[n]);
      h[n] = fmaf(h[n], e, du * bs[n]);
      float p = h[n] * cs[n];
      if ((n & 3) == 0) y0 += p; else if ((n & 3) == 1) y1 += p;
      else if ((n & 3) == 2) y2 += p; else y3 += p;
    }
    float yv = ((y0 + y1) + (y2 + y3)) + uv * Dd;
    y[base * DIN + d] = yv * siluf(zv);
  }
}

// ---------------- 13. out_proj + residual, f32 store ----------------
// (R2 root cause: output is FLOAT32 — reference is all-f32; bf16 stores filled
//  only half the buffer and packed two bf16 per f32 word.)
// grid (256 l-tiles of 64, B), block 256
__global__ __launch_bounds__(256) void k_outproj(const float* __restrict__ y,
    const float* __restrict__ Wout, const float* __restrict__ Lx,
    float* __restrict__ out) {
  __shared__ float yT[64 * 68];   // [k][l], stride 68
  __shared__ float w_t[96 * 65];  // [c][k], stride 65
  int b = blockIdx.y, l0 = blockIdx.x * 64;
  int tid = threadIdx.x, tx = tid & 15, ty = tid >> 4;
  float acc[6][4];
#pragma unroll
  for (int j = 0; j < 6; j++) { acc[j][0] = acc[j][1] = acc[j][2] = acc[j][3] = 0.f; }
  int lq = tid >> 2, kq = tid & 3;
  for (int cc = 0; cc < 3; cc++) {
#pragma unroll
    for (int it = 0; it < 4; it++) {
      int k = kq * 4 + it * 16;
      float4 v = *(const float4*)&y[((size_t)(b * LSEQ + l0 + lq)) * DIN + cc * 64 + k];
      yT[(k + 0) * 68 + lq] = v.x;
      yT[(k + 1) * 68 + lq] = v.y;
      yT[(k + 2) * 68 + lq] = v.z;
      yT[(k + 3) * 68 + lq] = v.w;
    }
    for (int i = tid; i < 96 * 64; i += 256) {
      int c = i >> 6, k = i & 63;
      w_t[c * 65 + k] = Wout[(size_t)c * DIN + cc * 64 + k];
    }
    __syncthreads();
#pragma unroll 4
    for (int k = 0; k < 64; k++) {
      float4 lv = *(const float4*)&yT[k * 68 + tx * 4];
#pragma unroll
      for (int j = 0; j < 6; j++) {
        float wv = w_t[(ty * 6 + j) * 65 + k];
        acc[j][0] = fmaf(wv, lv.x, acc[j][0]);
        acc[j][1] = fmaf(wv, lv.y, acc[j][1]);
        acc[j][2] = fmaf(wv, lv.z, acc[j][2]);
        acc[j][3] = fmaf(wv, lv.w, acc[j][3]);
      }
    }
    __syncthreads();
  }
#pragma unroll
  for (int j = 0; j < 6; j++) {
    int c = ty * 6 + j;
    size_t oidx = ((size_t)b * 96 + c) * LSEQ + l0 + tx * 4;
    float4 r = *(const float4*)&Lx[oidx];
    float4 o = make_float4(acc[j][0] + r.x, acc[j][1] + r.y,
                           acc[j][2] + r.z, acc[j][3] + r.w);
    *(float4*)&out[oidx] = o;
  }
}

// ---------------- launch ----------------
extern "C" void kernel_launch(void* const* d_in, const int* in_sizes, int n_in,
                              void* d_out, int out_size, void* d_ws, size_t ws_size,
                              hipStream_t stream) {
  (void)in_sizes; (void)n_in; (void)out_size; (void)ws_size;
  const float* x    = (const float*)d_in[0];
  const float* Hx   = (const float*)d_in[1];
  const float* c1w  = (const float*)d_in[2];
  const float* c1b  = (const float*)d_in[3];
  const float* c2w  = (const float*)d_in[4];
  const float* c2b  = (const float*)d_in[5];
  const float* c3w  = (const float*)d_in[6];
  const float* c3b  = (const float*)d_in[7];
  const float* Win  = (const float*)d_in[8];
  const float* w1d  = (const float*)d_in[9];
  const float* b1d  = (const float*)d_in[10];
  const float* Wx   = (const float*)d_in[11];
  const float* Wdt  = (const float*)d_in[12];
  const float* bdt  = (const float*)d_in[13];
  const float* Alog = (const float*)d_in[14];
  const float* Dp   = (const float*)d_in[15];
  const float* Wout = (const float*)d_in[16];
  float* out = (float*)d_out;

  float* ws = (float*)d_ws;
  const size_t F = (size_t)2 * 96 * LSEQ;      // 3,145,728 floats (12 MB), one [2,96,128,128]
  const size_t Fh = F / 2;                     // chunk-state size: 2*256*192*16 = 1,572,864
  const size_t XDBL = (size_t)2 * LSEQ * 38;   // 1,245,184

  // liveness plan (all offsets in floats):
  //  step                reads                     writes
  //  upsample            x                         up   [0,F)
  //  conv1 (288->96)     up, Hx                    h1   [F,2F)
  //  conv3x3             h1                        h2   [2F,3F)
  //  conv3 (96->96 1x1)  h2                        h3   [0,F)      (up dead)
  //  stats               h3                        st   [11F+XDBL, +384)
  //  normselu            h3, st                    Lx   [F,2F)     (h1 dead; Lx lives to end)
  //  inproj              Lx, Win                   xz   [3F,7F)
  //  conv1d              xz                        u    [7F,9F)
  //  xproj               u                         xdbl [9F, 9F+XDBL)
  //  dtproj              xdbl                      dt   [9F+XDBL, 11F+XDBL)
  //  scanA               dt,u,xdbl                 chA  [2F,2F+Fh), chB [2F+Fh,3F)   (h2 dead)
  //  scanB               chA,chB                   h0   [0,Fh)     (h3 dead)
  //  scanC               dt,u,xdbl,xz,h0           y = dt region, in-place (same-thread RAW)
  //  outproj             y, Wout, Lx               out
  float* b_up   = ws;
  float* b_h1   = ws + F;
  float* b_h2   = ws + 2 * F;
  float* b_h3   = ws;
  float* b_Lx   = ws + F;
  float* b_xz   = ws + 3 * F;
  float* b_u    = ws + 7 * F;
  float* b_xdbl = ws + 9 * F;
  float* b_dt   = ws + 9 * F + XDBL;
  float* b_st   = ws + 11 * F + XDBL;
  float* chA    = ws + 2 * F;
  float* chB    = ws + 2 * F + Fh;
  float* h0b    = ws;
  float* b_y    = b_dt;

  k_upsample<<<dim3(12288), dim3(256), 0, stream>>>(x, b_up);
  k_conv1x1<<<dim3(256, 2), dim3(256), 0, stream>>>(b_up, 96, Hx, 192, c1w, c1b, b_h1, 288);
  k_conv3x3<<<dim3(64, 6, 2), dim3(256), 0, stream>>>(b_h1, c2w, c2b, b_h2);
  k_conv1x1<<<dim3(256, 2), dim3(256), 0, stream>>>(b_h2, 96, (const float*)nullptr, 0, c3w, c3b, b_h3, 96);
  k_stats<<<dim3(192), dim3(256), 0, stream>>>(b_h3, b_st);
  k_normselu<<<dim3(12288), dim3(256), 0, stream>>>(b_h3, b_st, b_Lx);
  k_inproj<<<dim3(256, 3, 2), dim3(256), 0, stream>>>(b_Lx, Win, b_xz);
  k_conv1d<<<dim3((2 * LSEQ * DIN + 255) / 256), dim3(256), 0, stream>>>(b_xz, w1d, b1d, b_u);
  k_xproj<<<dim3((2 * LSEQ * 38 + 255) / 256), dim3(256), 0, stream>>>(b_u, Wx, b_xdbl);
  k_dtproj<<<dim3((2 * LSEQ * DIN + 255) / 256), dim3(256), 0, stream>>>(b_xdbl, Wdt, bdt, b_dt);
  k_scanA<<<dim3(GCH, 2), dim3(192), 0, stream>>>(b_dt, b_u, b_xdbl, Alog, chA, chB);
  k_scanB<<<dim3(24), dim3(256), 0, stream>>>(chA, chB, h0b);
  k_scanC<<<dim3(GCH, 2), dim3(192), 0, stream>>>(b_dt, b_u, b_xdbl, b_xz, Alog, Dp, h0b, b_y);
  k_outproj<<<dim3(256, 2), dim3(256), 0, stream>>>(b_y, Wout, b_Lx, out);
}

// Round 5
// 411.345 us; speedup vs baseline: 1.7308x; 1.7308x over previous
//
#include <hip/hip_runtime.h>
#include <hip/hip_bf16.h>
#include <math.h>

#define LSEQ 16384
#define DIN  192
#define GCH  256
#define TCH  64

typedef float f4v __attribute__((ext_vector_type(4)));
typedef short s8v __attribute__((ext_vector_type(8)));
typedef unsigned short u16x8 __attribute__((ext_vector_type(8)));

__device__ __forceinline__ float siluf(float x) { return x / (1.0f + __expf(-x)); }
__device__ __forceinline__ unsigned short f2bf(float f) {
  unsigned int u = __float_as_uint(f);
  unsigned int r = (u + 0x7FFFu + ((u >> 16) & 1u)) >> 16;
  return (unsigned short)r;
}
__device__ __forceinline__ float bf2f(unsigned short s) {
  return __uint_as_float(((unsigned int)s) << 16);
}

// ---------------- weight pre-pack to bf16 ----------------
// P: [0)Wc1p 96x288 | [27648)Wc2p 3x9x96x32 | [110592)Wc3p 96x96 |
//    [119808)Winp 384x96 | [156672)Wxp 48x192 (rows>=38 zero) | [165888)Woutp 96x192
__global__ __launch_bounds__(256) void k_packw(const float* __restrict__ c1w,
    const float* __restrict__ c2w, const float* __restrict__ c3w,
    const float* __restrict__ Win, const float* __restrict__ Wx,
    const float* __restrict__ Wout, unsigned short* __restrict__ P) {
  int i = blockIdx.x * 256 + threadIdx.x;
  if (i >= 184320) return;
  if (i < 27648) { P[i] = f2bf(c1w[i]); return; }
  int j = i - 27648;
  if (j < 82944) {
    int cc = j / 27648, r = j - cc * 27648;
    int kk = r / 3072, r2 = r - kk * 3072;
    int oc = r2 >> 5, icl = r2 & 31;
    int ky = kk / 3, kx = kk - ky * 3;
    P[i] = f2bf(c2w[((oc * 96 + cc * 32 + icl) * 3 + ky) * 3 + kx]);
    return;
  }
  j -= 82944;
  if (j < 9216) { P[i] = f2bf(c3w[j]); return; }
  j -= 9216;
  if (j < 36864) { P[i] = f2bf(Win[j]); return; }
  j -= 36864;
  if (j < 9216) {
    int oc = j / 192, k = j - oc * 192;
    P[i] = (oc < 38) ? f2bf(Wx[oc * 192 + k]) : (unsigned short)0;
    return;
  }
  j -= 9216;
  P[i] = f2bf(Wout[j]);
}

// ---------------- bilinear upsample 2x (align_corners), f32 planar ----------------
__global__ __launch_bounds__(256) void k_upsample(const float* __restrict__ x, float* __restrict__ up) {
  int idx = blockIdx.x * 256 + threadIdx.x;
  if (idx >= 2 * 96 * LSEQ) return;
  int ow = idx & 127, oh = (idx >> 7) & 127, bc = idx >> 14;
  float pr = oh * (63.0f / 127.0f); int r0 = (int)pr; float rw = pr - (float)r0; int r1 = min(r0 + 1, 63);
  float pc = ow * (63.0f / 127.0f); int c0 = (int)pc; float cw = pc - (float)c0; int c1 = min(c0 + 1, 63);
  const float* xp = x + (size_t)bc * 4096;
  float v00 = xp[r0 * 64 + c0], v01 = xp[r0 * 64 + c1];
  float v10 = xp[r1 * 64 + c0], v11 = xp[r1 * 64 + c1];
  float top = v00 + (v10 - v00) * rw;
  float bot = v01 + (v11 - v01) * rw;
  up[idx] = top + (bot - top) * cw;
}

// ---------------- generic MFMA GEMM ----------------
// C[px 0..32767][oc 0..NT*16) = X[px][K] * W[oc][K]^T
// block: 128 px (8 m-tiles; wave w owns 2), NT n-tiles. K chunks of 96.
#define SRC_PLANAR2 0
#define SRC_ROWS    1
#define OUT_BF16R    0   // bf16 rows [px][96], +bias
#define OUT_F32P     1   // f32 planar [b][96][16384], +bias
#define OUT_F32R     2   // f32 rows stride ostride, col base oc0g, guard ng
#define OUT_BF16RG   3   // bf16 rows stride ostride, col base oc0g
#define OUT_F32P_RES 4   // f32 planar + residual

template<int SM, int OM, int NT>
__global__ __launch_bounds__(256) void k_gemm(
    const void* __restrict__ xa, const void* __restrict__ xb, int CA,
    const unsigned short* __restrict__ Wp, const float* __restrict__ bias,
    void* __restrict__ outv, const float* __restrict__ resid,
    int K, int ostride, int oc0g, int ng) {
  __shared__ unsigned short x_t[128 * 96];
  __shared__ unsigned short w_t[NT * 16 * 96];
  Wp += (size_t)blockIdx.y * 96 * K;       // oc-group slicing (inproj)
  oc0g += blockIdx.y * 96;
  int pxg0 = blockIdx.x * 128;
  int b = pxg0 >> 14, px_in0 = pxg0 & 16383;
  int tid = threadIdx.x, lane = tid & 63, wv = tid >> 6;
  int r = lane & 15, q = lane >> 4;
  f4v acc[2][NT];
#pragma unroll
  for (int mi = 0; mi < 2; mi++)
#pragma unroll
    for (int n = 0; n < NT; n++) acc[mi][n] = (f4v)0.0f;
  int nchunk = K / 96;
  for (int kc = 0; kc < nchunk; kc++) {
    for (int t = tid; t < NT * 16 * 12; t += 256) {
      int row = t / 12, u8 = t - row * 12;
      *(u16x8*)&w_t[row * 96 + u8 * 8] = *(const u16x8*)&Wp[(size_t)row * K + kc * 96 + u8 * 8];
    }
    if (SM == SRC_PLANAR2) {
      const float* A0 = (const float*)xa;
      const float* A1 = (const float*)xb;
      int CB = K - CA;
      for (int t = tid; t < 3072; t += 256) {
        int px4 = t / 96, c_l = t - px4 * 96;
        int c = kc * 96 + c_l;
        const float* sp = (c < CA) ? (A0 + ((size_t)b * CA + c) * LSEQ + px_in0 + px4 * 4)
                                   : (A1 + ((size_t)b * CB + (c - CA)) * LSEQ + px_in0 + px4 * 4);
        float4 v = *(const float4*)sp;
        x_t[(px4 * 4 + 0) * 96 + c_l] = f2bf(v.x);
        x_t[(px4 * 4 + 1) * 96 + c_l] = f2bf(v.y);
        x_t[(px4 * 4 + 2) * 96 + c_l] = f2bf(v.z);
        x_t[(px4 * 4 + 3) * 96 + c_l] = f2bf(v.w);
      }
    } else {
      const unsigned short* X = (const unsigned short*)xa;
      for (int t = tid; t < 1536; t += 256) {
        int rr = t / 12, u8 = t - rr * 12;
        *(u16x8*)&x_t[rr * 96 + u8 * 8] =
            *(const u16x8*)&X[(size_t)(pxg0 + rr) * K + kc * 96 + u8 * 8];
      }
    }
    __syncthreads();
#pragma unroll
    for (int k0 = 0; k0 < 96; k0 += 32) {
      s8v a0 = *(const s8v*)&x_t[((wv * 2 + 0) * 16 + r) * 96 + k0 + q * 8];
      s8v a1 = *(const s8v*)&x_t[((wv * 2 + 1) * 16 + r) * 96 + k0 + q * 8];
#pragma unroll
      for (int n = 0; n < NT; n++) {
        s8v bb = *(const s8v*)&w_t[(n * 16 + r) * 96 + k0 + q * 8];
        acc[0][n] = __builtin_amdgcn_mfma_f32_16x16x32_bf16(a0, bb, acc[0][n], 0, 0, 0);
        acc[1][n] = __builtin_amdgcn_mfma_f32_16x16x32_bf16(a1, bb, acc[1][n], 0, 0, 0);
      }
    }
    __syncthreads();
  }
#pragma unroll
  for (int mi = 0; mi < 2; mi++) {
    int pxl = (wv * 2 + mi) * 16 + q * 4;
    int pxg = pxg0 + pxl;
#pragma unroll
    for (int n = 0; n < NT; n++) {
      int oc = n * 16 + r;
      if (OM == OUT_BF16R) {
        float bv = bias[oc];
        unsigned short* O = (unsigned short*)outv;
#pragma unroll
        for (int g = 0; g < 4; g++)
          O[(size_t)(pxg + g) * 96 + oc] = f2bf(acc[mi][n][g] + bv);
      } else if (OM == OUT_F32P) {
        float bv = bias[oc];
        float* O = (float*)outv;
        float4 o = make_float4(acc[mi][n][0] + bv, acc[mi][n][1] + bv,
                               acc[mi][n][2] + bv, acc[mi][n][3] + bv);
        *(float4*)&O[((size_t)b * 96 + oc) * LSEQ + px_in0 + pxl] = o;
      } else if (OM == OUT_F32P_RES) {
        float* O = (float*)outv;
        size_t ad = ((size_t)b * 96 + oc) * LSEQ + px_in0 + pxl;
        float4 rv = *(const float4*)&resid[ad];
        float4 o = make_float4(acc[mi][n][0] + rv.x, acc[mi][n][1] + rv.y,
                               acc[mi][n][2] + rv.z, acc[mi][n][3] + rv.w);
        *(float4*)&O[ad] = o;
      } else if (OM == OUT_F32R) {
        float* O = (float*)outv;
        int ocg = oc0g + oc;
        if (ocg < ng) {
#pragma unroll
          for (int g = 0; g < 4; g++)
            O[(size_t)(pxg + g) * ostride + ocg] = acc[mi][n][g];
        }
      } else { // OUT_BF16RG
        unsigned short* O = (unsigned short*)outv;
        int ocg = oc0g + oc;
#pragma unroll
        for (int g = 0; g < 4; g++)
          O[(size_t)(pxg + g) * ostride + ocg] = f2bf(acc[mi][n][g]);
      }
    }
  }
}

// ---------------- conv3x3 implicit-GEMM MFMA ----------------
__global__ __launch_bounds__(256) void k_conv3x3m(const unsigned short* __restrict__ X,
    const unsigned short* __restrict__ Wp2, const float* __restrict__ bias,
    unsigned short* __restrict__ out) {
  __shared__ unsigned short in_t[3 * 68 * 32];
  __shared__ unsigned short w_t[9 * 96 * 32];
  int bi = blockIdx.x;
  int hx = bi & 1, y = (bi >> 1) & 127, b = bi >> 8;
  int px0 = hx * 64;
  int tid = threadIdx.x, lane = tid & 63, wv = tid >> 6;
  int r = lane & 15, q = lane >> 4;
  f4v acc[6];
#pragma unroll
  for (int n = 0; n < 6; n++) acc[n] = (f4v)0.0f;
  for (int cc = 0; cc < 3; cc++) {
    for (int t = tid; t < 3456; t += 256)
      *(u16x8*)&w_t[t * 8] = *(const u16x8*)&Wp2[cc * 27648 + t * 8];
    for (int t = tid; t < 792; t += 256) {
      int row = t / 264, rem = t - row * 264;
      int c_l = rem >> 2, icq = rem & 3;
      int gy = y - 1 + row, gx = px0 - 1 + c_l;
      u16x8 v = {0, 0, 0, 0, 0, 0, 0, 0};
      if (gy >= 0 && gy < 128 && gx >= 0 && gx < 128)
        v = *(const u16x8*)&X[(((size_t)b * 128 + gy) * 128 + gx) * 96 + cc * 32 + icq * 8];
      *(u16x8*)&in_t[(row * 68 + c_l) * 32 + icq * 8] = v;
    }
    __syncthreads();
#pragma unroll
    for (int kk = 0; kk < 9; kk++) {
      int ky = kk / 3, kx = kk - ky * 3;
      s8v a = *(const s8v*)&in_t[(ky * 68 + wv * 16 + r + kx) * 32 + q * 8];
#pragma unroll
      for (int n = 0; n < 6; n++) {
        s8v bb = *(const s8v*)&w_t[(kk * 96 + n * 16 + r) * 32 + q * 8];
        acc[n] = __builtin_amdgcn_mfma_f32_16x16x32_bf16(a, bb, acc[n], 0, 0, 0);
      }
    }
    __syncthreads();
  }
  size_t rowbase = ((size_t)b * 128 + y) * 128 + px0 + wv * 16 + q * 4;
#pragma unroll
  for (int n = 0; n < 6; n++) {
    int oc = n * 16 + r;
    float bv = bias[oc];
#pragma unroll
    for (int g = 0; g < 4; g++)
      out[(rowbase + g) * 96 + oc] = f2bf(acc[n][g] + bv);
  }
}

// ---------------- instance-norm stats ----------------
__global__ __launch_bounds__(256) void k_stats(const float* __restrict__ h, float* __restrict__ stats) {
  int bc = blockIdx.x;
  const float* p = h + (size_t)bc * LSEQ;
  float s = 0.f, ss = 0.f;
  for (int i = threadIdx.x; i < LSEQ; i += 256) { float v = p[i]; s += v; ss = fmaf(v, v, ss); }
  __shared__ float rs[256], rss[256];
  int tid = threadIdx.x;
  rs[tid] = s; rss[tid] = ss; __syncthreads();
  for (int o = 128; o > 0; o >>= 1) {
    if (tid < o) { rs[tid] += rs[tid + o]; rss[tid] += rss[tid + o]; }
    __syncthreads();
  }
  if (tid == 0) {
    float m = rs[0] * (1.0f / LSEQ);
    float var = rss[0] * (1.0f / LSEQ) - m * m;
    stats[bc * 2] = m;
    stats[bc * 2 + 1] = rsqrtf(fmaxf(var, 0.f) + 1e-5f);
  }
}

// ---------------- normalize + SELU: planar f32 Lx + NHWC bf16 LxR ----------------
__global__ __launch_bounds__(256) void k_normselu2(const float* __restrict__ h,
    const float* __restrict__ stats, float* __restrict__ Lx, unsigned short* __restrict__ LxR) {
  __shared__ float tile[96 * 65];
  int px0 = blockIdx.x * 64, b = blockIdx.y;
  int tid = threadIdx.x;
  const float kS = 1.0507009873554805f, kA = 1.6732632423543772f;
  for (int t = tid; t < 1536; t += 256) {
    int c = t >> 4, p4 = t & 15;
    size_t ga = ((size_t)b * 96 + c) * LSEQ + px0 + p4 * 4;
    float4 v = *(const float4*)&h[ga];
    float m = stats[(b * 96 + c) * 2], rv = stats[(b * 96 + c) * 2 + 1];
    v.x = (v.x - m) * rv; v.y = (v.y - m) * rv; v.z = (v.z - m) * rv; v.w = (v.w - m) * rv;
    v.x = v.x > 0.f ? kS * v.x : kS * kA * expm1f(v.x);
    v.y = v.y > 0.f ? kS * v.y : kS * kA * expm1f(v.y);
    v.z = v.z > 0.f ? kS * v.z : kS * kA * expm1f(v.z);
    v.w = v.w > 0.f ? kS * v.w : kS * kA * expm1f(v.w);
    *(float4*)&Lx[ga] = v;
    tile[c * 65 + p4 * 4 + 0] = v.x;
    tile[c * 65 + p4 * 4 + 1] = v.y;
    tile[c * 65 + p4 * 4 + 2] = v.z;
    tile[c * 65 + p4 * 4 + 3] = v.w;
  }
  __syncthreads();
  for (int t = tid; t < 768; t += 256) {
    int px = t / 12, c8 = t - px * 12;
    u16x8 o;
#pragma unroll
    for (int jj = 0; jj < 8; jj++) o[jj] = f2bf(tile[(c8 * 8 + jj) * 65 + px]);
    *(u16x8*)&LxR[((size_t)b * LSEQ + px0 + px) * 96 + c8 * 8] = o;
  }
}

// ---------------- causal depthwise conv1d + SiLU ----------------
__global__ __launch_bounds__(256) void k_conv1d(const float* __restrict__ xzx,
    const float* __restrict__ w1d, const float* __restrict__ b1d,
    float* __restrict__ u, unsigned short* __restrict__ uR) {
  int gid = blockIdx.x * 256 + threadIdx.x;
  if (gid >= 2 * LSEQ * DIN) return;
  int d = gid % DIN, bl = gid / DIN;
  int l = bl & (LSEQ - 1);
  float4 w = *(const float4*)&w1d[d * 4];
  float wv[4] = {w.x, w.y, w.z, w.w};
  float acc = b1d[d];
#pragma unroll
  for (int k = 0; k < 4; k++) {
    int lk = l - 3 + k;
    if (lk >= 0) acc = fmaf(wv[k], xzx[(size_t)(bl - 3 + k) * DIN + d], acc);
  }
  float s = siluf(acc);
  u[gid] = s;
  uR[gid] = f2bf(s);
}

// ---------------- dt_proj + softplus ----------------
__global__ __launch_bounds__(256) void k_dtproj(const float* __restrict__ xdbl,
    const float* __restrict__ Wdt, const float* __restrict__ bdt, float* __restrict__ dt) {
  int gid = blockIdx.x * 256 + threadIdx.x;
  if (gid >= 2 * LSEQ * DIN) return;
  int d = gid % DIN, bl = gid / DIN;
  const float* xp = xdbl + (size_t)bl * 38;
  const float* wp = Wdt + d * 6;
  float acc = bdt[d];
#pragma unroll
  for (int r = 0; r < 6; r++) acc = fmaf(xp[r], wp[r], acc);
  dt[gid] = acc > 20.f ? acc : log1pf(__expf(acc));
}

// ---------------- scan phase A ----------------
__global__ __launch_bounds__(192) void k_scanA(const float* __restrict__ dt,
    const float* __restrict__ u, const float* __restrict__ xdbl,
    const float* __restrict__ Alog, float* __restrict__ chA, float* __restrict__ chB) {
  int b = blockIdx.y, g = blockIdx.x, d = threadIdx.x;
  __shared__ float Bs[TCH * 16];
  for (int i = threadIdx.x; i < TCH * 16; i += 192) {
    int t = i >> 4, n = i & 15;
    Bs[i] = xdbl[(size_t)(b * LSEQ + g * TCH + t) * 38 + 6 + n];
  }
  float ac[16];
#pragma unroll
  for (int n = 0; n < 16; n++) ac[n] = -__expf(Alog[d * 16 + n]);
  __syncthreads();
  float ap[16], hb[16];
#pragma unroll
  for (int n = 0; n < 16; n++) { ap[n] = 1.f; hb[n] = 0.f; }
  for (int t = 0; t < TCH; t++) {
    size_t base = (size_t)(b * LSEQ + g * TCH + t);
    float dtv = dt[base * DIN + d];
    float uv = u[base * DIN + d];
    float du = dtv * uv;
    float bs[16];
    const float4* src = (const float4*)&Bs[t * 16];
#pragma unroll
    for (int qq = 0; qq < 4; qq++) {
      float4 v = src[qq];
      bs[qq * 4] = v.x; bs[qq * 4 + 1] = v.y; bs[qq * 4 + 2] = v.z; bs[qq * 4 + 3] = v.w;
    }
#pragma unroll
    for (int n = 0; n < 16; n++) {
      float e = __expf(dtv * ac[n]);
      ap[n] *= e;
      hb[n] = fmaf(hb[n], e, du * bs[n]);
    }
  }
  size_t co = ((size_t)(b * GCH + g) * DIN + d) * 16;
#pragma unroll
  for (int qq = 0; qq < 4; qq++) {
    ((float4*)(chA + co))[qq] = make_float4(ap[qq * 4], ap[qq * 4 + 1], ap[qq * 4 + 2], ap[qq * 4 + 3]);
    ((float4*)(chB + co))[qq] = make_float4(hb[qq * 4], hb[qq * 4 + 1], hb[qq * 4 + 2], hb[qq * 4 + 3]);
  }
}

// ---------------- scan phase B ----------------
__global__ __launch_bounds__(256) void k_scanB(const float* __restrict__ chA,
    const float* __restrict__ chB, float* __restrict__ h0) {
  int tid = blockIdx.x * 256 + threadIdx.x;
  if (tid >= 2 * DIN * 16) return;
  int b = tid / (DIN * 16), rem = tid - b * DIN * 16;
  float h = 0.f;
#pragma unroll 4
  for (int g = 0; g < GCH; g++) {
    size_t off = (size_t)(b * GCH + g) * (DIN * 16) + rem;
    h0[off] = h;
    h = fmaf(h, chA[off], chB[off]);
  }
}

// ---------------- scan phase C: replay + gate, bf16 y rows ----------------
__global__ __launch_bounds__(192) void k_scanC(const float* __restrict__ dt,
    const float* __restrict__ u, const float* __restrict__ xdbl,
    const unsigned short* __restrict__ zR, const float* __restrict__ Alog,
    const float* __restrict__ Dp, const float* __restrict__ h0, unsigned short* __restrict__ yR) {
  int b = blockIdx.y, g = blockIdx.x, d = threadIdx.x;
  __shared__ float Bs[TCH * 16], Cs[TCH * 16];
  for (int i = threadIdx.x; i < TCH * 16; i += 192) {
    int t = i >> 4, n = i & 15;
    size_t rb = (size_t)(b * LSEQ + g * TCH + t) * 38;
    Bs[i] = xdbl[rb + 6 + n];
    Cs[i] = xdbl[rb + 22 + n];
  }
  float ac[16];
#pragma unroll
  for (int n = 0; n < 16; n++) ac[n] = -__expf(Alog[d * 16 + n]);
  float Dd = Dp[d];
  __syncthreads();
  size_t co = ((size_t)(b * GCH + g) * DIN + d) * 16;
  float h[16];
#pragma unroll
  for (int qq = 0; qq < 4; qq++) {
    float4 v = ((const float4*)(h0 + co))[qq];
    h[qq * 4] = v.x; h[qq * 4 + 1] = v.y; h[qq * 4 + 2] = v.z; h[qq * 4 + 3] = v.w;
  }
  for (int t = 0; t < TCH; t++) {
    size_t base = (size_t)(b * LSEQ + g * TCH + t);
    float dtv = dt[base * DIN + d];
    float uv = u[base * DIN + d];
    float zv = bf2f(zR[base * DIN + d]);
    float du = dtv * uv;
    float bs[16], cs[16];
    const float4* sb = (const float4*)&Bs[t * 16];
    const float4* sc = (const float4*)&Cs[t * 16];
#pragma unroll
    for (int qq = 0; qq < 4; qq++) {
      float4 vb = sb[qq], vc = sc[qq];
      bs[qq * 4] = vb.x; bs[qq * 4 + 1] = vb.y; bs[qq * 4 + 2] = vb.z; bs[qq * 4 + 3] = vb.w;
      cs[qq * 4] = vc.x; cs[qq * 4 + 1] = vc.y; cs[qq * 4 + 2] = vc.z; cs[qq * 4 + 3] = vc.w;
    }
    float y0 = 0.f, y1 = 0.f, y2 = 0.f, y3 = 0.f;
#pragma unroll
    for (int n = 0; n < 16; n++) {
      float e = __expf(dtv * ac[n]);
      h[n] = fmaf(h[n], e, du * bs[n]);
      float p = h[n] * cs[n];
      if ((n & 3) == 0) y0 += p; else if ((n & 3) == 1) y1 += p;
      else if ((n & 3) == 2) y2 += p; else y3 += p;
    }
    float yv = ((y0 + y1) + (y2 + y3)) + uv * Dd;
    yR[base * DIN + d] = f2bf(yv * siluf(zv));
  }
}

// ---------------- launch ----------------
extern "C" void kernel_launch(void* const* d_in, const int* in_sizes, int n_in,
                              void* d_out, int out_size, void* d_ws, size_t ws_size,
                              hipStream_t stream) {
  (void)in_sizes; (void)n_in; (void)out_size; (void)ws_size;
  const float* x    = (const float*)d_in[0];
  const float* Hx   = (const float*)d_in[1];
  const float* c1w  = (const float*)d_in[2];
  const float* c1b  = (const float*)d_in[3];
  const float* c2w  = (const float*)d_in[4];
  const float* c2b  = (const float*)d_in[5];
  const float* c3w  = (const float*)d_in[6];
  const float* c3b  = (const float*)d_in[7];
  const float* Win  = (const float*)d_in[8];
  const float* w1d  = (const float*)d_in[9];
  const float* b1d  = (const float*)d_in[10];
  const float* Wx   = (const float*)d_in[11];
  const float* Wdt  = (const float*)d_in[12];
  const float* bdt  = (const float*)d_in[13];
  const float* Alog = (const float*)d_in[14];
  const float* Dp   = (const float*)d_in[15];
  const float* Wout = (const float*)d_in[16];
  float* out = (float*)d_out;

  float* ws = (float*)d_ws;
  const size_t F = (size_t)2 * 96 * LSEQ;      // 3,145,728 floats
  const size_t Fh = F / 2;
  const size_t XDBL = (size_t)2 * LSEQ * 38;

  // R4 bugfix: 192-wide bf16 row buffers (uR/yR/zR) are F floats, not Fh.
  // layout (floats), total 9F + XDBL + 92,544 ~= 118.6 MB:
  //  [0,F)        up -> h3 -> chA|chB        (up dead after conv1; h3 dead after normselu2)
  //  [F,2F)       Lx (f32 planar, lives to outproj)
  //  [2F,2.5F)    R1: h1 bf16 rows96 -> LxR bf16 rows96
  //  [2.5F,3F)    R2: h2 bf16 rows96 -> h0 (f32, scanB; h2 dead after conv3-1x1)
  //  [3F,5F)      xzx f32 rows192 -> dt f32 (xzx dead after conv1d; dt written after)
  //  [5F,6F)      zR bf16 rows192 (inproj-z .. scanC)
  //  [6F,7F)      R3: uR bf16 rows192 (conv1d .. xproj) -> yR bf16 rows192 (scanC .. outproj)
  //  [7F,9F)      u f32 rows192 (conv1d .. scanC)
  //  [9F,+XDBL)   xdbl f32 rows38
  //  [+92160]     Wp bf16 weights   [+384] stats
  float*          b_up = ws;
  float*          b_h3 = ws;
  float*          chA  = ws;
  float*          chB  = ws + Fh;
  float*          b_Lx = ws + F;
  unsigned short* R1   = (unsigned short*)(ws + 2 * F);
  unsigned short* R2   = (unsigned short*)(ws + 2 * F + Fh);
  float*          h0b  = ws + 2 * F + Fh;
  float*          xzx  = ws + 3 * F;
  float*          b_dt = ws + 3 * F;
  unsigned short* zRb  = (unsigned short*)(ws + 5 * F);
  unsigned short* R3   = (unsigned short*)(ws + 6 * F);
  float*          b_u  = ws + 7 * F;
  float*          xdbl = ws + 9 * F;
  unsigned short* Wp   = (unsigned short*)(ws + 9 * F + XDBL);
  float*          b_st = ws + 9 * F + XDBL + 92160;

  k_packw<<<dim3(720), dim3(256), 0, stream>>>(c1w, c2w, c3w, Win, Wx, Wout, Wp);
  k_upsample<<<dim3(12288), dim3(256), 0, stream>>>(x, b_up);
  k_gemm<SRC_PLANAR2, OUT_BF16R, 6><<<dim3(256, 1), dim3(256), 0, stream>>>(
      b_up, Hx, 96, Wp, c1b, R1, nullptr, 288, 0, 0, 0);
  k_conv3x3m<<<dim3(512), dim3(256), 0, stream>>>(R1, Wp + 27648, c2b, R2);
  k_gemm<SRC_ROWS, OUT_F32P, 6><<<dim3(256, 1), dim3(256), 0, stream>>>(
      R2, nullptr, 0, Wp + 110592, c3b, b_h3, nullptr, 96, 0, 0, 0);
  k_stats<<<dim3(192), dim3(256), 0, stream>>>(b_h3, b_st);
  k_normselu2<<<dim3(256, 2), dim3(256), 0, stream>>>(b_h3, b_st, b_Lx, R1);
  k_gemm<SRC_ROWS, OUT_F32R, 6><<<dim3(256, 2), dim3(256), 0, stream>>>(
      R1, nullptr, 0, Wp + 119808, nullptr, xzx, nullptr, 96, 192, 0, 1 << 30);
  k_gemm<SRC_ROWS, OUT_BF16RG, 6><<<dim3(256, 2), dim3(256), 0, stream>>>(
      R1, nullptr, 0, Wp + 119808 + 192 * 96, nullptr, zRb, nullptr, 96, 192, 0, 0);
  k_conv1d<<<dim3((2 * LSEQ * DIN + 255) / 256), dim3(256), 0, stream>>>(xzx, w1d, b1d, b_u, R3);
  k_gemm<SRC_ROWS, OUT_F32R, 3><<<dim3(256, 1), dim3(256), 0, stream>>>(
      R3, nullptr, 0, Wp + 156672, nullptr, xdbl, nullptr, 192, 38, 0, 38);
  k_dtproj<<<dim3((2 * LSEQ * DIN + 255) / 256), dim3(256), 0, stream>>>(xdbl, Wdt, bdt, b_dt);
  k_scanA<<<dim3(GCH, 2), dim3(192), 0, stream>>>(b_dt, b_u, xdbl, Alog, chA, chB);
  k_scanB<<<dim3(24), dim3(256), 0, stream>>>(chA, chB, h0b);
  k_scanC<<<dim3(GCH, 2), dim3(192), 0, stream>>>(b_dt, b_u, xdbl, zRb, Alog, Dp, h0b, R3);
  k_gemm<SRC_ROWS, OUT_F32P_RES, 6><<<dim3(256, 1), dim3(256), 0, stream>>>(
      R3, nullptr, 0, Wp + 165888, nullptr, out, b_Lx, 192, 0, 0, 0);
}